// Round 12
// baseline (456.479 us; speedup 1.0000x reference)
//
#include <hip/hip_runtime.h>
#include <hip/hip_fp16.h>
#include <math.h>

#define NEG_SLOPE 0.2f
#define DEG_CAP 128

typedef __attribute__((ext_vector_type(8))) short      s16x8_t;
typedef __attribute__((ext_vector_type(8))) _Float16   f16x8_t;
typedef __attribute__((ext_vector_type(4))) float      f32x4_t;

struct __align__(8) half4_t { __half2 a, b; };

// ---------------------------------------------------------------------------
// prep0: zero cursor + as2b/ad2b; convert x->xf fp16, W1->w1t, W2->w2t
// (transposed); compute layer-1 logits asb1[i]=x_i·(W1@as1), adb1 likewise
// (w1s/w1d computed per-block in LDS; fused with the x read).  C==128 assumed.
// ---------------------------------------------------------------------------
__global__ __launch_bounds__(256) void prep0_k(
    int* __restrict__ cursor, float* __restrict__ zero2n, int n,
    const float* __restrict__ x, __half* __restrict__ xf,
    const float* __restrict__ W1, __half* __restrict__ w1t,
    const float* __restrict__ W2, __half* __restrict__ w2t,
    const float* __restrict__ as1, const float* __restrict__ ad1,
    float* __restrict__ asb1, float* __restrict__ adb1,
    int C, int d1, int d2)
{
    __shared__ float w1s[128], w1d[128];
    const int tid = threadIdx.x;
    {   // per-block w1s/w1d: w1s[k] = sum_n W1[k,n]*as1[n]
        int k = tid & 127;
        const float* av = (tid < 128) ? as1 : ad1;
        const float* wr = W1 + (size_t)k * d1;
        float s = 0.f;
        for (int nn = 0; nn < d1; nn++) s = fmaf(wr[nn], av[nn], s);
        if (tid < 128) w1s[k] = s; else w1d[k] = s;
    }
    __syncthreads();

    const int gid = blockIdx.x * 256 + tid;
    const int gsz = gridDim.x * 256;

    for (int i = gid; i < n; i += gsz) cursor[i] = 0;
    for (int i = gid; i < 2 * n; i += gsz) zero2n[i] = 0.f;   // as2b, ad2b
    for (int i = gid; i < C * d1; i += gsz) {
        int k = i / d1, c = i - k * d1;
        w1t[(size_t)c * C + k] = __float2half(W1[i]);
    }
    for (int i = gid; i < d1 * d2; i += gsz) {
        int k = i / d2, c = i - k * d2;
        w2t[(size_t)c * d1 + k] = __float2half(W2[i]);
    }
    // wave per row: fp16 convert + logit dots (x read once for both)
    const int wvid = gid >> 6, lane = gid & 63, nw = gsz >> 6;
    for (int row = wvid; row < n; row += nw) {
        float2 v = *(const float2*)(x + (size_t)row * C + (lane << 1));
        *(__half2*)(xf + (size_t)row * C + (lane << 1)) = __floats2half2_rn(v.x, v.y);
        float s = v.x * w1s[lane << 1] + v.y * w1s[(lane << 1) + 1];
        float d = v.x * w1d[lane << 1] + v.y * w1d[(lane << 1) + 1];
#pragma unroll
        for (int o = 32; o; o >>= 1) { s += __shfl_xor(s, o); d += __shfl_xor(d, o); }
        if (lane == 0) { asb1[row] = s; adb1[row] = d; }
    }
}

// ---------------------------------------------------------------------------
// CSR build: histogram -> block scan -> scatter fill
// ---------------------------------------------------------------------------
__global__ void hist_k(const int* __restrict__ ei, int E, int n, int* __restrict__ deg) {
    int e = blockIdx.x * 256 + threadIdx.x;
    int ET = E + n;
    if (e >= ET) return;
    int d = (e < E) ? ei[E + e] : (e - E);
    atomicAdd(&deg[d], 1);
}

__global__ void scan1_k(const int* __restrict__ deg, int* __restrict__ incl,
                        int* __restrict__ bsums, int n) {
    __shared__ int s[256];
    int tid = threadIdx.x;
    int i = blockIdx.x * 256 + tid;
    int v = (i < n) ? deg[i] : 0;
    s[tid] = v;
    __syncthreads();
    for (int off = 1; off < 256; off <<= 1) {
        int t = (tid >= off) ? s[tid - off] : 0;
        __syncthreads();
        s[tid] += t;
        __syncthreads();
    }
    if (i < n) incl[i] = s[tid];
    if (tid == 255) bsums[blockIdx.x] = s[255];
}

__global__ void scan2_k(int* __restrict__ bsums, int nch) {
    __shared__ int s[256];
    int tid = threadIdx.x;
    int v = (tid < nch) ? bsums[tid] : 0;
    int orig = v;
    s[tid] = v;
    __syncthreads();
    for (int off = 1; off < 256; off <<= 1) {
        int t = (tid >= off) ? s[tid - off] : 0;
        __syncthreads();
        s[tid] += t;
        __syncthreads();
    }
    if (tid < nch) bsums[tid] = s[tid] - orig;  // exclusive
}

__global__ void scan3_k(int* __restrict__ offsets, int* __restrict__ cursor,
                        const int* __restrict__ bsums, int n, int total) {
    int i = blockIdx.x * 256 + threadIdx.x;
    if (i < n) {
        int excl = offsets[i] - cursor[i] + bsums[i >> 8];
        offsets[i] = excl;
        cursor[i]  = excl;
    }
    if (i == 0 && blockIdx.x == 0) offsets[n] = total;
}

__global__ void fill_k(const int* __restrict__ ei, int E, int n,
                       int* __restrict__ cursor, int* __restrict__ csr) {
    int e = blockIdx.x * 256 + threadIdx.x;
    int ET = E + n;
    if (e >= ET) return;
    int s, d;
    if (e < E) { s = ei[e]; d = ei[E + e]; }
    else       { s = e - E; d = e - E; }
    int pos = atomicAdd(&cursor[d], 1);
    csr[pos] = s;
}

// ---------------------------------------------------------------------------
// agg1x: aggregate in x-space (D=128 fp16, 256B/row gather).
// Two passes (weights+sum, gather), 4-way unroll, writes z fp16.
// No bias/ELU here (moved to gemm1: out1 = ELU(z@W1 + b1)).
// ---------------------------------------------------------------------------
__global__ __launch_bounds__(256) void agg1x_k(
    const int* __restrict__ offs, const int* __restrict__ csr,
    const float* __restrict__ asb, const float* __restrict__ adb,
    const __half* __restrict__ xf, __half* __restrict__ z, int n)
{
    __shared__ float wsh[4][DEG_CAP];
    __shared__ int   osh[4][DEG_CAP];
    const int wv = threadIdx.x >> 6, lane = threadIdx.x & 63;
    const int wid = (blockIdx.x << 2) + wv;
    const bool active = wid < n;

    int beg = 0, deg = 0;
    float adi = 0.f;
    if (active) { beg = offs[wid]; deg = offs[wid + 1] - beg; adi = adb[wid]; }
    const int degc = deg < DEG_CAP ? deg : DEG_CAP;

    float inv = 0.f;
    if (active) {
        float ssum = 0.f;
        for (int e = lane; e < degc; e += 64) {
            int j = csr[beg + e];
            float v = asb[j] + adi;
            v = v > 0.f ? v : NEG_SLOPE * v;
            v = fminf(fmaxf(v, -60.f), 60.f);
            float w = __expf(v);
            osh[wv][e] = j << 8;          // j * 256 bytes (128 halfs)
            wsh[wv][e] = w;
            ssum += w;
        }
        for (int e = DEG_CAP + lane; e < deg; e += 64) {
            float v = asb[csr[beg + e]] + adi;
            v = v > 0.f ? v : NEG_SLOPE * v;
            v = fminf(fmaxf(v, -60.f), 60.f);
            ssum += __expf(v);
        }
#pragma unroll
        for (int o = 32; o; o >>= 1) ssum += __shfl_xor(ssum, o);
        inv = 1.f / ssum;
    }

    __syncthreads();
    if (!active) return;

    float c0 = 0.f, d0 = 0.f, c1 = 0.f, d1a = 0.f, c2 = 0.f, d2a = 0.f, c3 = 0.f, d3a = 0.f;
    const char* hb = (const char*)xf + (lane << 2);   // 4B per lane

    int e = 0;
    for (; e + 4 <= degc; e += 4) {
        int o0 = osh[wv][e], o1 = osh[wv][e + 1], o2 = osh[wv][e + 2], o3 = osh[wv][e + 3];
        float w0 = wsh[wv][e], w1 = wsh[wv][e + 1], w2 = wsh[wv][e + 2], w3 = wsh[wv][e + 3];
        float2 f0 = __half22float2(*(const __half2*)(hb + o0));
        float2 f1 = __half22float2(*(const __half2*)(hb + o1));
        float2 f2 = __half22float2(*(const __half2*)(hb + o2));
        float2 f3 = __half22float2(*(const __half2*)(hb + o3));
        c0 = fmaf(w0, f0.x, c0); d0 = fmaf(w0, f0.y, d0);
        c1 = fmaf(w1, f1.x, c1); d1a = fmaf(w1, f1.y, d1a);
        c2 = fmaf(w2, f2.x, c2); d2a = fmaf(w2, f2.y, d2a);
        c3 = fmaf(w3, f3.x, c3); d3a = fmaf(w3, f3.y, d3a);
    }
    for (; e < degc; ++e) {
        int o0 = osh[wv][e];
        float w0 = wsh[wv][e];
        float2 f0 = __half22float2(*(const __half2*)(hb + o0));
        c0 = fmaf(w0, f0.x, c0); d0 = fmaf(w0, f0.y, d0);
    }
    for (int eo = DEG_CAP; eo < deg; ++eo) {
        int j = csr[beg + eo];
        float v = asb[j] + adi;
        v = v > 0.f ? v : NEG_SLOPE * v;
        v = fminf(fmaxf(v, -60.f), 60.f);
        float w0 = __expf(v);
        float2 f0 = __half22float2(*(const __half2*)(hb + (j << 8)));
        c0 = fmaf(w0, f0.x, c0); d0 = fmaf(w0, f0.y, d0);
    }

    float t0 = (c0 + c1 + c2 + c3) * inv;
    float t1 = (d0 + d1a + d2a + d3a) * inv;
    *(__half2*)(z + (size_t)wid * 128 + (lane << 1)) = __floats2half2_rn(t0, t1);
}

// ---------------------------------------------------------------------------
// fp16 MFMA GEMM.  EPI=true (layer1): out = ELU(acc + b1) fp16, plus fused
// layer-2 logit atomics via per-block LDS w2s/w2d (= W2 @ as2 / ad2 slices).
// EPI=false (layer2): plain fp16 store of acc.
// block tile 128x64, 4 waves (2Mx2N), wave tile 64x32, BK=32.
// ---------------------------------------------------------------------------
template <bool EPI>
__device__ __forceinline__ void gemm_core(const ushort* __restrict__ A,
                                          const ushort* __restrict__ BT,
                                          __half* __restrict__ Ch,
                                          int M, int K, int Nc,
                                          const float* __restrict__ bias,
                                          const float* __restrict__ W2, int d2,
                                          const float* __restrict__ av_s,
                                          const float* __restrict__ av_d,
                                          float* __restrict__ asb_o,
                                          float* __restrict__ adb_o) {
    __shared__ __align__(16) ushort sA[128][40];
    __shared__ __align__(16) ushort sB[64][40];
    __shared__ float w2s[64], w2d[64];

    const int tid  = threadIdx.x;
    const int lane = tid & 63;
    const int wv   = tid >> 6;
    const int wm   = wv & 1, wn = wv >> 1;
    const int m0   = blockIdx.x << 7;
    const int n0   = blockIdx.y << 6;

    if (EPI && tid < 128) {
        // w2s[c-n0] = sum_m W2[c,m]*as2[m] for this block's 64 cols
        int c = n0 + (tid & 63);
        const float* av = (tid < 64) ? av_s : av_d;
        const float* wr = W2 + (size_t)c * d2;
        float s = 0.f;
        for (int m = 0; m < d2; m++) s = fmaf(wr[m], av[m], s);
        ((tid < 64) ? w2s : w2d)[tid & 63] = s;
    }

    f32x4_t acc[4][2];
#pragma unroll
    for (int i = 0; i < 4; i++)
#pragma unroll
        for (int j = 0; j < 2; j++) acc[i][j] = (f32x4_t){0.f, 0.f, 0.f, 0.f};

    const int arow = tid >> 1;
    const int acb  = (tid & 1) << 4;
    const int brow = tid >> 2;
    const int bkb  = (tid & 3) << 3;

    const s16x8_t zv = {};

    for (int k0 = 0; k0 < K; k0 += 32) {
        {
            const int gr = m0 + arow;
            s16x8_t v0 = zv, v1 = zv;
            if (gr < M) {
                const ushort* pa = A + (size_t)gr * K + k0 + acb;
                v0 = *(const s16x8_t*)pa;
                v1 = *(const s16x8_t*)(pa + 8);
            }
            *(s16x8_t*)&sA[arow][acb]     = v0;
            *(s16x8_t*)&sA[arow][acb + 8] = v1;
        }
        {
            const ushort* pb = BT + (size_t)(n0 + brow) * K + k0 + bkb;
            *(s16x8_t*)&sB[brow][bkb] = *(const s16x8_t*)pb;
        }
        __syncthreads();
        f16x8_t af[4], bf[2];
        const int rbase = (wm << 6) + (lane & 15);
        const int slot  = (lane >> 4) << 3;
#pragma unroll
        for (int mi = 0; mi < 4; mi++)
            af[mi] = *(const f16x8_t*)&sA[rbase + (mi << 4)][slot];
        const int cbase = (wn << 5) + (lane & 15);
#pragma unroll
        for (int ni = 0; ni < 2; ni++)
            bf[ni] = *(const f16x8_t*)&sB[cbase + (ni << 4)][slot];
#pragma unroll
        for (int mi = 0; mi < 4; mi++)
#pragma unroll
            for (int ni = 0; ni < 2; ni++)
                acc[mi][ni] = __builtin_amdgcn_mfma_f32_16x16x32_f16(af[mi], bf[ni], acc[mi][ni], 0, 0, 0);
        __syncthreads();
    }

    // epilogue: C/D layout col=lane&15, row=(lane>>4)*4+reg
    const int col0 = n0 + (wn << 5) + (lane & 15);
    float bv0 = 0.f, bv1 = 0.f, ws0 = 0.f, ws1 = 0.f, wd0 = 0.f, wd1 = 0.f;
    if (EPI) {
        bv0 = bias[col0]; bv1 = bias[col0 + 16];
        ws0 = w2s[col0 - n0]; ws1 = w2s[col0 + 16 - n0];
        wd0 = w2d[col0 - n0]; wd1 = w2d[col0 + 16 - n0];
    }

#pragma unroll
    for (int mi = 0; mi < 4; mi++) {
        const int row0 = m0 + (wm << 6) + (mi << 4) + ((lane >> 4) << 2);
        float e0[4], e1[4];
#pragma unroll
        for (int r = 0; r < 4; r++) {
            float v0 = acc[mi][0][r], v1 = acc[mi][1][r];
            if (EPI) {
                v0 += bv0; v0 = v0 > 0.f ? v0 : expm1f(v0);
                v1 += bv1; v1 = v1 > 0.f ? v1 : expm1f(v1);
            }
            e0[r] = v0; e1[r] = v1;
            if (row0 + r < M) {
                Ch[(size_t)(row0 + r) * Nc + col0]      = __float2half(v0);
                Ch[(size_t)(row0 + r) * Nc + col0 + 16] = __float2half(v1);
            }
        }
        if (EPI) {
            float ss[4], sd[4];
#pragma unroll
            for (int r = 0; r < 4; r++) {
                ss[r] = e0[r] * ws0 + e1[r] * ws1;
                sd[r] = e0[r] * wd0 + e1[r] * wd1;
            }
#pragma unroll
            for (int off = 1; off < 16; off <<= 1) {
#pragma unroll
                for (int r = 0; r < 4; r++) {
                    ss[r] += __shfl_xor(ss[r], off);
                    sd[r] += __shfl_xor(sd[r], off);
                }
            }
            if ((lane & 15) == 0) {
#pragma unroll
                for (int r = 0; r < 4; r++)
                    if (row0 + r < M) {
                        atomicAdd(&asb_o[row0 + r], ss[r]);
                        atomicAdd(&adb_o[row0 + r], sd[r]);
                    }
            }
        }
    }
}

__global__ __launch_bounds__(256) void gemm1_k(const ushort* A, const ushort* BT,
                                               __half* Ch, int M, int K, int Nc,
                                               const float* bias, const float* W2, int d2,
                                               const float* av_s, const float* av_d,
                                               float* asb_o, float* adb_o) {
    gemm_core<true>(A, BT, Ch, M, K, Nc, bias, W2, d2, av_s, av_d, asb_o, adb_o);
}
__global__ __launch_bounds__(256) void gemm2_k(const ushort* A, const ushort* BT,
                                               __half* Ch, int M, int K, int Nc) {
    gemm_core<false>(A, BT, Ch, M, K, Nc, nullptr, nullptr, 0, nullptr, nullptr, nullptr, nullptr);
}

// ---------------------------------------------------------------------------
// agg2: D=64 fp16 gather, +b2, ELU, fused layer-3 prep (h3 = out2·W3 etc.)
// ---------------------------------------------------------------------------
__global__ __launch_bounds__(256) void agg2_k(
    const int* __restrict__ offs, const int* __restrict__ csr,
    const float* __restrict__ asb, const float* __restrict__ adb,
    const __half* __restrict__ h, const float* __restrict__ b2,
    const float* __restrict__ W3, const float* __restrict__ as3,
    const float* __restrict__ ad3,
    float* __restrict__ h3o, float* __restrict__ as3b, float* __restrict__ ad3b, int n)
{
    __shared__ float wsh[4][DEG_CAP];
    __shared__ int   osh[4][DEG_CAP];
    const int wv = threadIdx.x >> 6, lane = threadIdx.x & 63;
    const int wid = (blockIdx.x << 2) + wv;
    const bool active = wid < n;

    int beg = 0, deg = 0;
    float adi = 0.f;
    if (active) { beg = offs[wid]; deg = offs[wid + 1] - beg; adi = adb[wid]; }
    const int degc = deg < DEG_CAP ? deg : DEG_CAP;

    float inv = 0.f;
    if (active) {
        float ssum = 0.f;
        for (int e = lane; e < degc; e += 64) {
            int j = csr[beg + e];
            float v = asb[j] + adi;
            v = v > 0.f ? v : NEG_SLOPE * v;
            v = fminf(fmaxf(v, -60.f), 60.f);
            float w = __expf(v);
            osh[wv][e] = j << 7;          // j * 128 bytes (64 halfs)
            wsh[wv][e] = w;
            ssum += w;
        }
        for (int e = DEG_CAP + lane; e < deg; e += 64) {
            float v = asb[csr[beg + e]] + adi;
            v = v > 0.f ? v : NEG_SLOPE * v;
            v = fminf(fmaxf(v, -60.f), 60.f);
            ssum += __expf(v);
        }
#pragma unroll
        for (int o = 32; o; o >>= 1) ssum += __shfl_xor(ssum, o);
        inv = 1.f / ssum;
    }

    __syncthreads();
    if (!active) return;

    float c0 = 0.f, c1 = 0.f, c2 = 0.f, c3 = 0.f;
    const char* hb = (const char*)h + (lane << 1);

    int e = 0;
    for (; e + 4 <= degc; e += 4) {
        int o0 = osh[wv][e], o1 = osh[wv][e + 1], o2 = osh[wv][e + 2], o3 = osh[wv][e + 3];
        float w0 = wsh[wv][e], w1 = wsh[wv][e + 1], w2 = wsh[wv][e + 2], w3 = wsh[wv][e + 3];
        c0 = fmaf(w0, __half2float(*(const __half*)(hb + o0)), c0);
        c1 = fmaf(w1, __half2float(*(const __half*)(hb + o1)), c1);
        c2 = fmaf(w2, __half2float(*(const __half*)(hb + o2)), c2);
        c3 = fmaf(w3, __half2float(*(const __half*)(hb + o3)), c3);
    }
    for (; e < degc; ++e)
        c0 = fmaf(wsh[wv][e], __half2float(*(const __half*)(hb + osh[wv][e])), c0);
    for (int eo = DEG_CAP; eo < deg; ++eo) {
        int j = csr[beg + eo];
        float v = asb[j] + adi;
        v = v > 0.f ? v : NEG_SLOPE * v;
        v = fminf(fmaxf(v, -60.f), 60.f);
        c0 = fmaf(__expf(v), __half2float(*(const __half*)(hb + (j << 7))), c0);
    }

    float t = (c0 + c1 + c2 + c3) * inv + b2[lane];
    t = t > 0.f ? t : expm1f(t);
    float c = t * W3[lane];
#pragma unroll
    for (int o = 32; o; o >>= 1) c += __shfl_xor(c, o);
    if (lane == 0) {
        h3o[wid]  = c;
        as3b[wid] = c * as3[0];
        ad3b[wid] = c * ad3[0];
    }
}

// ---------------------------------------------------------------------------
// layer 3 aggregation: single pass
// ---------------------------------------------------------------------------
__global__ void agg3_k(const int* __restrict__ offs, const int* __restrict__ csr,
                       const float* __restrict__ asb, const float* __restrict__ adb,
                       const float* __restrict__ h3, const float* __restrict__ b3,
                       float* __restrict__ out, int n) {
    int wid = (blockIdx.x << 2) + (threadIdx.x >> 6);
    int lane = threadIdx.x & 63;
    if (wid >= n) return;
    int beg = offs[wid], end = offs[wid + 1];
    float adi = adb[wid];

    float ssum = 0.f, acc = 0.f;
    for (int e = beg + lane; e < end; e += 64) {
        int j = csr[e];
        float v = asb[j] + adi;
        v = v > 0.f ? v : NEG_SLOPE * v;
        v = fminf(fmaxf(v, -60.f), 60.f);
        float w = __expf(v);
        ssum += w;
        acc = fmaf(w, h3[j], acc);
    }
#pragma unroll
    for (int o = 32; o; o >>= 1) {
        ssum += __shfl_xor(ssum, o);
        acc  += __shfl_xor(acc, o);
    }
    if (lane == 0) out[wid] = acc / ssum + b3[0];
}

// ---------------------------------------------------------------------------
extern "C" void kernel_launch(void* const* d_in, const int* in_sizes, int n_in,
                              void* d_out, int out_size, void* d_ws, size_t ws_size,
                              hipStream_t stream) {
    const float* x   = (const float*)d_in[0];
    const int*   ei  = (const int*)d_in[1];
    const float* W1  = (const float*)d_in[2];
    const float* as1 = (const float*)d_in[3];
    const float* ad1 = (const float*)d_in[4];
    const float* b1  = (const float*)d_in[5];
    const float* W2  = (const float*)d_in[6];
    const float* as2 = (const float*)d_in[7];
    const float* ad2 = (const float*)d_in[8];
    const float* b2  = (const float*)d_in[9];
    const float* W3  = (const float*)d_in[10];
    const float* as3 = (const float*)d_in[11];
    const float* ad3 = (const float*)d_in[12];
    const float* b3  = (const float*)d_in[13];

    const int d1 = in_sizes[3];                    // 256
    const int C  = in_sizes[2] / d1;               // 128
    const int N  = in_sizes[0] / C;                // 50000
    const int E  = in_sizes[1] / 2;                // 800000
    const int d2 = in_sizes[7];                    // 64
    const int ET = E + N;                          // 850000

    char* p = (char*)d_ws;
    auto alloc = [&](size_t bytes) -> void* {
        void* q = (void*)p;
        p += (bytes + 255) & ~(size_t)255;
        return q;
    };
    int*    offsets = (int*)alloc(sizeof(int) * (size_t)(N + 1));
    int*    cursor  = (int*)alloc(sizeof(int) * (size_t)N);
    int*    bsums   = (int*)alloc(sizeof(int) * 256);
    int*    csr     = (int*)alloc(sizeof(int) * (size_t)ET);
    float*  asb1    = (float*)alloc(sizeof(float) * (size_t)N);
    float*  adb1    = (float*)alloc(sizeof(float) * (size_t)N);
    float*  alpha2  = (float*)alloc(sizeof(float) * (size_t)2 * N);  // as2b, ad2b
    float*  as2b = alpha2, *ad2b = alpha2 + N;
    __half* xf      = (__half*)alloc(sizeof(__half) * (size_t)N * C);
    __half* zbuf    = (__half*)alloc(sizeof(__half) * (size_t)N * C);
    __half* w1t     = (__half*)alloc(sizeof(__half) * (size_t)C * d1);
    __half* w2t     = (__half*)alloc(sizeof(__half) * (size_t)d1 * d2);
    __half* o1      = (__half*)alloc(sizeof(__half) * (size_t)N * d1);
    __half* ch2     = (__half*)alloc(sizeof(__half) * (size_t)N * d2);
    float*  h3      = (float*)alloc(sizeof(float) * (size_t)N);
    float*  as3b    = (float*)alloc(sizeof(float) * (size_t)N);
    float*  ad3b    = (float*)alloc(sizeof(float) * (size_t)N);

    const int eb  = (ET + 255) / 256;
    const int nch = (N + 255) / 256;
    const int wb  = (N + 3) / 4;

    // ---- prep0: zero + converts + layer-1 logits ----
    prep0_k<<<1024, 256, 0, stream>>>(cursor, alpha2, N,
                                      x, xf, W1, w1t, W2, w2t,
                                      as1, ad1, asb1, adb1, C, d1, d2);

    // ---- CSR build ----
    hist_k<<<eb, 256, 0, stream>>>(ei, E, N, cursor);
    scan1_k<<<nch, 256, 0, stream>>>(cursor, offsets, bsums, N);
    scan2_k<<<1, 256, 0, stream>>>(bsums, nch);
    scan3_k<<<nch, 256, 0, stream>>>(offsets, cursor, bsums, N, ET);
    fill_k<<<eb, 256, 0, stream>>>(ei, E, N, cursor, csr);

    // ---- layer 1: aggregate x (128-dim), then GEMM with fused bias+ELU+logits ----
    agg1x_k<<<wb, 256, 0, stream>>>(offsets, csr, asb1, adb1, xf, zbuf, N);
    {
        dim3 g((N + 127) / 128, d1 / 64);
        gemm1_k<<<g, 256, 0, stream>>>((const ushort*)zbuf, (const ushort*)w1t,
                                       o1, N, C, d1, b1, W2, d2, as2, ad2, as2b, ad2b);
    }
    // ---- layer 2: GEMM (256->64), aggregate 64-dim, fused layer-3 prep ----
    {
        dim3 g((N + 127) / 128, d2 / 64);
        gemm2_k<<<g, 256, 0, stream>>>((const ushort*)o1, (const ushort*)w2t,
                                       ch2, N, d1, d2);
    }
    agg2_k<<<wb, 256, 0, stream>>>(offsets, csr, as2b, ad2b, ch2, b2,
                                   W3, as3, ad3, h3, as3b, ad3b, N);
    // ---- layer 3: aggregation ----
    agg3_k<<<wb, 256, 0, stream>>>(offsets, csr, as3b, ad3b, h3, b3, (float*)d_out, N);
}

// Round 13
// 334.684 us; speedup vs baseline: 1.3639x; 1.3639x over previous
//
#include <hip/hip_runtime.h>
#include <hip/hip_fp16.h>
#include <math.h>

#define NEG_SLOPE 0.2f
#define DEG_CAP 128

typedef __attribute__((ext_vector_type(8))) short      s16x8_t;
typedef __attribute__((ext_vector_type(8))) _Float16   f16x8_t;
typedef __attribute__((ext_vector_type(4))) float      f32x4_t;

struct __align__(8) half4_t { __half2 a, b; };

// ---------------------------------------------------------------------------
// wvec_k: ONE block computes w1s[128] = W1 @ as1, w1d[128] = W1 @ ad1.
// Thread-per-k, contiguous float4 row reads (W1 row k is 1KB contiguous).
// ---------------------------------------------------------------------------
__global__ __launch_bounds__(256) void wvec_k(const float* __restrict__ W1,
                                              const float* __restrict__ as1,
                                              const float* __restrict__ ad1,
                                              float* __restrict__ wvec,
                                              int C, int d1) {
    const int tid = threadIdx.x;
    const int k = tid & 127;
    if (k >= C) return;
    const float* av = (tid < 128) ? as1 : ad1;
    const float* wr = W1 + (size_t)k * d1;
    float s = 0.f;
    for (int nn = 0; nn < d1; nn += 4) {
        float4 w4 = *(const float4*)(wr + nn);
        float4 a4 = *(const float4*)(av + nn);
        s += w4.x * a4.x + w4.y * a4.y + w4.z * a4.z + w4.w * a4.w;
    }
    wvec[(tid < 128 ? 0 : 128) + k] = s;
}

// ---------------------------------------------------------------------------
// prep0: zero cursor + as2b/ad2b; convert x->xf fp16, W1->w1t, W2->w2t
// (transposed); layer-1 logits asb1[i]=x_i·w1s, adb1[i]=x_i·w1d with
// w1s/w1d read from global wvec (computed once by wvec_k).  C==128 assumed.
// ---------------------------------------------------------------------------
__global__ __launch_bounds__(256) void prep0_k(
    int* __restrict__ cursor, float* __restrict__ zero2n, int n,
    const float* __restrict__ x, __half* __restrict__ xf,
    const float* __restrict__ W1, __half* __restrict__ w1t,
    const float* __restrict__ W2, __half* __restrict__ w2t,
    const float* __restrict__ wvec,
    float* __restrict__ asb1, float* __restrict__ adb1,
    int C, int d1, int d2)
{
    const int tid = threadIdx.x;
    const int gid = blockIdx.x * 256 + tid;
    const int gsz = gridDim.x * 256;
    const int lane = tid & 63;

    // per-lane logit weights (4 broadcast loads, L2-cached)
    const float ws0 = wvec[lane << 1],         ws1 = wvec[(lane << 1) + 1];
    const float wd0 = wvec[128 + (lane << 1)], wd1 = wvec[128 + (lane << 1) + 1];

    for (int i = gid; i < n; i += gsz) cursor[i] = 0;
    for (int i = gid; i < 2 * n; i += gsz) zero2n[i] = 0.f;   // as2b, ad2b
    for (int i = gid; i < C * d1; i += gsz) {
        int k = i / d1, c = i - k * d1;
        w1t[(size_t)c * C + k] = __float2half(W1[i]);
    }
    for (int i = gid; i < d1 * d2; i += gsz) {
        int k = i / d2, c = i - k * d2;
        w2t[(size_t)c * d1 + k] = __float2half(W2[i]);
    }
    // wave per row: fp16 convert + logit dots (x read once for both)
    const int wvid = gid >> 6, nw = gsz >> 6;
    for (int row = wvid; row < n; row += nw) {
        float2 v = *(const float2*)(x + (size_t)row * C + (lane << 1));
        *(__half2*)(xf + (size_t)row * C + (lane << 1)) = __floats2half2_rn(v.x, v.y);
        float s = v.x * ws0 + v.y * ws1;
        float d = v.x * wd0 + v.y * wd1;
#pragma unroll
        for (int o = 32; o; o >>= 1) { s += __shfl_xor(s, o); d += __shfl_xor(d, o); }
        if (lane == 0) { asb1[row] = s; adb1[row] = d; }
    }
}

// ---------------------------------------------------------------------------
// CSR build: histogram -> block scan -> scatter fill
// ---------------------------------------------------------------------------
__global__ void hist_k(const int* __restrict__ ei, int E, int n, int* __restrict__ deg) {
    int e = blockIdx.x * 256 + threadIdx.x;
    int ET = E + n;
    if (e >= ET) return;
    int d = (e < E) ? ei[E + e] : (e - E);
    atomicAdd(&deg[d], 1);
}

__global__ void scan1_k(const int* __restrict__ deg, int* __restrict__ incl,
                        int* __restrict__ bsums, int n) {
    __shared__ int s[256];
    int tid = threadIdx.x;
    int i = blockIdx.x * 256 + tid;
    int v = (i < n) ? deg[i] : 0;
    s[tid] = v;
    __syncthreads();
    for (int off = 1; off < 256; off <<= 1) {
        int t = (tid >= off) ? s[tid - off] : 0;
        __syncthreads();
        s[tid] += t;
        __syncthreads();
    }
    if (i < n) incl[i] = s[tid];
    if (tid == 255) bsums[blockIdx.x] = s[255];
}

__global__ void scan2_k(int* __restrict__ bsums, int nch) {
    __shared__ int s[256];
    int tid = threadIdx.x;
    int v = (tid < nch) ? bsums[tid] : 0;
    int orig = v;
    s[tid] = v;
    __syncthreads();
    for (int off = 1; off < 256; off <<= 1) {
        int t = (tid >= off) ? s[tid - off] : 0;
        __syncthreads();
        s[tid] += t;
        __syncthreads();
    }
    if (tid < nch) bsums[tid] = s[tid] - orig;  // exclusive
}

__global__ void scan3_k(int* __restrict__ offsets, int* __restrict__ cursor,
                        const int* __restrict__ bsums, int n, int total) {
    int i = blockIdx.x * 256 + threadIdx.x;
    if (i < n) {
        int excl = offsets[i] - cursor[i] + bsums[i >> 8];
        offsets[i] = excl;
        cursor[i]  = excl;
    }
    if (i == 0 && blockIdx.x == 0) offsets[n] = total;
}

__global__ void fill_k(const int* __restrict__ ei, int E, int n,
                       int* __restrict__ cursor, int* __restrict__ csr) {
    int e = blockIdx.x * 256 + threadIdx.x;
    int ET = E + n;
    if (e >= ET) return;
    int s, d;
    if (e < E) { s = ei[e]; d = ei[E + e]; }
    else       { s = e - E; d = e - E; }
    int pos = atomicAdd(&cursor[d], 1);
    csr[pos] = s;
}

// ---------------------------------------------------------------------------
// agg1x: aggregate in x-space (D=128 fp16, 256B/row gather).
// Two passes (weights+sum, gather), 4-way unroll, writes z fp16.
// No bias/ELU here (moved to gemm1: out1 = ELU(z@W1 + b1)).
// ---------------------------------------------------------------------------
__global__ __launch_bounds__(256) void agg1x_k(
    const int* __restrict__ offs, const int* __restrict__ csr,
    const float* __restrict__ asb, const float* __restrict__ adb,
    const __half* __restrict__ xf, __half* __restrict__ z, int n)
{
    __shared__ float wsh[4][DEG_CAP];
    __shared__ int   osh[4][DEG_CAP];
    const int wv = threadIdx.x >> 6, lane = threadIdx.x & 63;
    const int wid = (blockIdx.x << 2) + wv;
    const bool active = wid < n;

    int beg = 0, deg = 0;
    float adi = 0.f;
    if (active) { beg = offs[wid]; deg = offs[wid + 1] - beg; adi = adb[wid]; }
    const int degc = deg < DEG_CAP ? deg : DEG_CAP;

    float inv = 0.f;
    if (active) {
        float ssum = 0.f;
        for (int e = lane; e < degc; e += 64) {
            int j = csr[beg + e];
            float v = asb[j] + adi;
            v = v > 0.f ? v : NEG_SLOPE * v;
            v = fminf(fmaxf(v, -60.f), 60.f);
            float w = __expf(v);
            osh[wv][e] = j << 8;          // j * 256 bytes (128 halfs)
            wsh[wv][e] = w;
            ssum += w;
        }
        for (int e = DEG_CAP + lane; e < deg; e += 64) {
            float v = asb[csr[beg + e]] + adi;
            v = v > 0.f ? v : NEG_SLOPE * v;
            v = fminf(fmaxf(v, -60.f), 60.f);
            ssum += __expf(v);
        }
#pragma unroll
        for (int o = 32; o; o >>= 1) ssum += __shfl_xor(ssum, o);
        inv = 1.f / ssum;
    }

    __syncthreads();
    if (!active) return;

    float c0 = 0.f, d0 = 0.f, c1 = 0.f, d1a = 0.f, c2 = 0.f, d2a = 0.f, c3 = 0.f, d3a = 0.f;
    const char* hb = (const char*)xf + (lane << 2);   // 4B per lane

    int e = 0;
    for (; e + 4 <= degc; e += 4) {
        int o0 = osh[wv][e], o1 = osh[wv][e + 1], o2 = osh[wv][e + 2], o3 = osh[wv][e + 3];
        float w0 = wsh[wv][e], w1 = wsh[wv][e + 1], w2 = wsh[wv][e + 2], w3 = wsh[wv][e + 3];
        float2 f0 = __half22float2(*(const __half2*)(hb + o0));
        float2 f1 = __half22float2(*(const __half2*)(hb + o1));
        float2 f2 = __half22float2(*(const __half2*)(hb + o2));
        float2 f3 = __half22float2(*(const __half2*)(hb + o3));
        c0 = fmaf(w0, f0.x, c0); d0 = fmaf(w0, f0.y, d0);
        c1 = fmaf(w1, f1.x, c1); d1a = fmaf(w1, f1.y, d1a);
        c2 = fmaf(w2, f2.x, c2); d2a = fmaf(w2, f2.y, d2a);
        c3 = fmaf(w3, f3.x, c3); d3a = fmaf(w3, f3.y, d3a);
    }
    for (; e < degc; ++e) {
        int o0 = osh[wv][e];
        float w0 = wsh[wv][e];
        float2 f0 = __half22float2(*(const __half2*)(hb + o0));
        c0 = fmaf(w0, f0.x, c0); d0 = fmaf(w0, f0.y, d0);
    }
    for (int eo = DEG_CAP; eo < deg; ++eo) {
        int j = csr[beg + eo];
        float v = asb[j] + adi;
        v = v > 0.f ? v : NEG_SLOPE * v;
        v = fminf(fmaxf(v, -60.f), 60.f);
        float w0 = __expf(v);
        float2 f0 = __half22float2(*(const __half2*)(hb + (j << 8)));
        c0 = fmaf(w0, f0.x, c0); d0 = fmaf(w0, f0.y, d0);
    }

    float t0 = (c0 + c1 + c2 + c3) * inv;
    float t1 = (d0 + d1a + d2a + d3a) * inv;
    *(__half2*)(z + (size_t)wid * 128 + (lane << 1)) = __floats2half2_rn(t0, t1);
}

// ---------------------------------------------------------------------------
// fp16 MFMA GEMM.  EPI=true (layer1): out = ELU(acc + b1) fp16, plus fused
// layer-2 logit atomics via per-block LDS w2s/w2d (= W2 @ as2 / ad2 slices).
// EPI=false (layer2): plain fp16 store of acc.
// block tile 128x64, 4 waves (2Mx2N), wave tile 64x32, BK=32.
// ---------------------------------------------------------------------------
template <bool EPI>
__device__ __forceinline__ void gemm_core(const ushort* __restrict__ A,
                                          const ushort* __restrict__ BT,
                                          __half* __restrict__ Ch,
                                          int M, int K, int Nc,
                                          const float* __restrict__ bias,
                                          const float* __restrict__ W2, int d2,
                                          const float* __restrict__ av_s,
                                          const float* __restrict__ av_d,
                                          float* __restrict__ asb_o,
                                          float* __restrict__ adb_o) {
    __shared__ __align__(16) ushort sA[128][40];
    __shared__ __align__(16) ushort sB[64][40];
    __shared__ float w2s[64], w2d[64];

    const int tid  = threadIdx.x;
    const int lane = tid & 63;
    const int wv   = tid >> 6;
    const int wm   = wv & 1, wn = wv >> 1;
    const int m0   = blockIdx.x << 7;
    const int n0   = blockIdx.y << 6;

    if (EPI && tid < 128) {
        // w2s[c-n0] = sum_m W2[c,m]*as2[m] for this block's 64 cols
        int c = n0 + (tid & 63);
        const float* av = (tid < 64) ? av_s : av_d;
        const float* wr = W2 + (size_t)c * d2;
        float s = 0.f;
        for (int m = 0; m < d2; m += 4) {
            float4 w4 = *(const float4*)(wr + m);
            float4 a4 = *(const float4*)(av + m);
            s += w4.x * a4.x + w4.y * a4.y + w4.z * a4.z + w4.w * a4.w;
        }
        ((tid < 64) ? w2s : w2d)[tid & 63] = s;
    }

    f32x4_t acc[4][2];
#pragma unroll
    for (int i = 0; i < 4; i++)
#pragma unroll
        for (int j = 0; j < 2; j++) acc[i][j] = (f32x4_t){0.f, 0.f, 0.f, 0.f};

    const int arow = tid >> 1;
    const int acb  = (tid & 1) << 4;
    const int brow = tid >> 2;
    const int bkb  = (tid & 3) << 3;

    const s16x8_t zv = {};

    for (int k0 = 0; k0 < K; k0 += 32) {
        {
            const int gr = m0 + arow;
            s16x8_t v0 = zv, v1 = zv;
            if (gr < M) {
                const ushort* pa = A + (size_t)gr * K + k0 + acb;
                v0 = *(const s16x8_t*)pa;
                v1 = *(const s16x8_t*)(pa + 8);
            }
            *(s16x8_t*)&sA[arow][acb]     = v0;
            *(s16x8_t*)&sA[arow][acb + 8] = v1;
        }
        {
            const ushort* pb = BT + (size_t)(n0 + brow) * K + k0 + bkb;
            *(s16x8_t*)&sB[brow][bkb] = *(const s16x8_t*)pb;
        }
        __syncthreads();
        f16x8_t af[4], bf[2];
        const int rbase = (wm << 6) + (lane & 15);
        const int slot  = (lane >> 4) << 3;
#pragma unroll
        for (int mi = 0; mi < 4; mi++)
            af[mi] = *(const f16x8_t*)&sA[rbase + (mi << 4)][slot];
        const int cbase = (wn << 5) + (lane & 15);
#pragma unroll
        for (int ni = 0; ni < 2; ni++)
            bf[ni] = *(const f16x8_t*)&sB[cbase + (ni << 4)][slot];
#pragma unroll
        for (int mi = 0; mi < 4; mi++)
#pragma unroll
            for (int ni = 0; ni < 2; ni++)
                acc[mi][ni] = __builtin_amdgcn_mfma_f32_16x16x32_f16(af[mi], bf[ni], acc[mi][ni], 0, 0, 0);
        __syncthreads();
    }

    // epilogue: C/D layout col=lane&15, row=(lane>>4)*4+reg
    const int col0 = n0 + (wn << 5) + (lane & 15);
    float bv0 = 0.f, bv1 = 0.f, ws0 = 0.f, ws1 = 0.f, wd0 = 0.f, wd1 = 0.f;
    if (EPI) {
        bv0 = bias[col0]; bv1 = bias[col0 + 16];
        ws0 = w2s[col0 - n0]; ws1 = w2s[col0 + 16 - n0];
        wd0 = w2d[col0 - n0]; wd1 = w2d[col0 + 16 - n0];
    }

#pragma unroll
    for (int mi = 0; mi < 4; mi++) {
        const int row0 = m0 + (wm << 6) + (mi << 4) + ((lane >> 4) << 2);
        float e0[4], e1[4];
#pragma unroll
        for (int r = 0; r < 4; r++) {
            float v0 = acc[mi][0][r], v1 = acc[mi][1][r];
            if (EPI) {
                v0 += bv0; v0 = v0 > 0.f ? v0 : expm1f(v0);
                v1 += bv1; v1 = v1 > 0.f ? v1 : expm1f(v1);
            }
            e0[r] = v0; e1[r] = v1;
            if (row0 + r < M) {
                Ch[(size_t)(row0 + r) * Nc + col0]      = __float2half(v0);
                Ch[(size_t)(row0 + r) * Nc + col0 + 16] = __float2half(v1);
            }
        }
        if (EPI) {
            float ss[4], sd[4];
#pragma unroll
            for (int r = 0; r < 4; r++) {
                ss[r] = e0[r] * ws0 + e1[r] * ws1;
                sd[r] = e0[r] * wd0 + e1[r] * wd1;
            }
#pragma unroll
            for (int off = 1; off < 16; off <<= 1) {
#pragma unroll
                for (int r = 0; r < 4; r++) {
                    ss[r] += __shfl_xor(ss[r], off);
                    sd[r] += __shfl_xor(sd[r], off);
                }
            }
            if ((lane & 15) == 0) {
#pragma unroll
                for (int r = 0; r < 4; r++)
                    if (row0 + r < M) {
                        atomicAdd(&asb_o[row0 + r], ss[r]);
                        atomicAdd(&adb_o[row0 + r], sd[r]);
                    }
            }
        }
    }
}

__global__ __launch_bounds__(256) void gemm1_k(const ushort* A, const ushort* BT,
                                               __half* Ch, int M, int K, int Nc,
                                               const float* bias, const float* W2, int d2,
                                               const float* av_s, const float* av_d,
                                               float* asb_o, float* adb_o) {
    gemm_core<true>(A, BT, Ch, M, K, Nc, bias, W2, d2, av_s, av_d, asb_o, adb_o);
}
__global__ __launch_bounds__(256) void gemm2_k(const ushort* A, const ushort* BT,
                                               __half* Ch, int M, int K, int Nc) {
    gemm_core<false>(A, BT, Ch, M, K, Nc, nullptr, nullptr, 0, nullptr, nullptr, nullptr, nullptr);
}

// ---------------------------------------------------------------------------
// agg2: D=64 fp16 gather, +b2, ELU, fused layer-3 prep (h3 = out2·W3 etc.)
// ---------------------------------------------------------------------------
__global__ __launch_bounds__(256) void agg2_k(
    const int* __restrict__ offs, const int* __restrict__ csr,
    const float* __restrict__ asb, const float* __restrict__ adb,
    const __half* __restrict__ h, const float* __restrict__ b2,
    const float* __restrict__ W3, const float* __restrict__ as3,
    const float* __restrict__ ad3,
    float* __restrict__ h3o, float* __restrict__ as3b, float* __restrict__ ad3b, int n)
{
    __shared__ float wsh[4][DEG_CAP];
    __shared__ int   osh[4][DEG_CAP];
    const int wv = threadIdx.x >> 6, lane = threadIdx.x & 63;
    const int wid = (blockIdx.x << 2) + wv;
    const bool active = wid < n;

    int beg = 0, deg = 0;
    float adi = 0.f;
    if (active) { beg = offs[wid]; deg = offs[wid + 1] - beg; adi = adb[wid]; }
    const int degc = deg < DEG_CAP ? deg : DEG_CAP;

    float inv = 0.f;
    if (active) {
        float ssum = 0.f;
        for (int e = lane; e < degc; e += 64) {
            int j = csr[beg + e];
            float v = asb[j] + adi;
            v = v > 0.f ? v : NEG_SLOPE * v;
            v = fminf(fmaxf(v, -60.f), 60.f);
            float w = __expf(v);
            osh[wv][e] = j << 7;          // j * 128 bytes (64 halfs)
            wsh[wv][e] = w;
            ssum += w;
        }
        for (int e = DEG_CAP + lane; e < deg; e += 64) {
            float v = asb[csr[beg + e]] + adi;
            v = v > 0.f ? v : NEG_SLOPE * v;
            v = fminf(fmaxf(v, -60.f), 60.f);
            ssum += __expf(v);
        }
#pragma unroll
        for (int o = 32; o; o >>= 1) ssum += __shfl_xor(ssum, o);
        inv = 1.f / ssum;
    }

    __syncthreads();
    if (!active) return;

    float c0 = 0.f, c1 = 0.f, c2 = 0.f, c3 = 0.f;
    const char* hb = (const char*)h + (lane << 1);

    int e = 0;
    for (; e + 4 <= degc; e += 4) {
        int o0 = osh[wv][e], o1 = osh[wv][e + 1], o2 = osh[wv][e + 2], o3 = osh[wv][e + 3];
        float w0 = wsh[wv][e], w1 = wsh[wv][e + 1], w2 = wsh[wv][e + 2], w3 = wsh[wv][e + 3];
        c0 = fmaf(w0, __half2float(*(const __half*)(hb + o0)), c0);
        c1 = fmaf(w1, __half2float(*(const __half*)(hb + o1)), c1);
        c2 = fmaf(w2, __half2float(*(const __half*)(hb + o2)), c2);
        c3 = fmaf(w3, __half2float(*(const __half*)(hb + o3)), c3);
    }
    for (; e < degc; ++e)
        c0 = fmaf(wsh[wv][e], __half2float(*(const __half*)(hb + osh[wv][e])), c0);
    for (int eo = DEG_CAP; eo < deg; ++eo) {
        int j = csr[beg + eo];
        float v = asb[j] + adi;
        v = v > 0.f ? v : NEG_SLOPE * v;
        v = fminf(fmaxf(v, -60.f), 60.f);
        c0 = fmaf(__expf(v), __half2float(*(const __half*)(hb + (j << 7))), c0);
    }

    float t = (c0 + c1 + c2 + c3) * inv + b2[lane];
    t = t > 0.f ? t : expm1f(t);
    float c = t * W3[lane];
#pragma unroll
    for (int o = 32; o; o >>= 1) c += __shfl_xor(c, o);
    if (lane == 0) {
        h3o[wid]  = c;
        as3b[wid] = c * as3[0];
        ad3b[wid] = c * ad3[0];
    }
}

// ---------------------------------------------------------------------------
// layer 3 aggregation: single pass
// ---------------------------------------------------------------------------
__global__ void agg3_k(const int* __restrict__ offs, const int* __restrict__ csr,
                       const float* __restrict__ asb, const float* __restrict__ adb,
                       const float* __restrict__ h3, const float* __restrict__ b3,
                       float* __restrict__ out, int n) {
    int wid = (blockIdx.x << 2) + (threadIdx.x >> 6);
    int lane = threadIdx.x & 63;
    if (wid >= n) return;
    int beg = offs[wid], end = offs[wid + 1];
    float adi = adb[wid];

    float ssum = 0.f, acc = 0.f;
    for (int e = beg + lane; e < end; e += 64) {
        int j = csr[e];
        float v = asb[j] + adi;
        v = v > 0.f ? v : NEG_SLOPE * v;
        v = fminf(fmaxf(v, -60.f), 60.f);
        float w = __expf(v);
        ssum += w;
        acc = fmaf(w, h3[j], acc);
    }
#pragma unroll
    for (int o = 32; o; o >>= 1) {
        ssum += __shfl_xor(ssum, o);
        acc  += __shfl_xor(acc, o);
    }
    if (lane == 0) out[wid] = acc / ssum + b3[0];
}

// ---------------------------------------------------------------------------
extern "C" void kernel_launch(void* const* d_in, const int* in_sizes, int n_in,
                              void* d_out, int out_size, void* d_ws, size_t ws_size,
                              hipStream_t stream) {
    const float* x   = (const float*)d_in[0];
    const int*   ei  = (const int*)d_in[1];
    const float* W1  = (const float*)d_in[2];
    const float* as1 = (const float*)d_in[3];
    const float* ad1 = (const float*)d_in[4];
    const float* b1  = (const float*)d_in[5];
    const float* W2  = (const float*)d_in[6];
    const float* as2 = (const float*)d_in[7];
    const float* ad2 = (const float*)d_in[8];
    const float* b2  = (const float*)d_in[9];
    const float* W3  = (const float*)d_in[10];
    const float* as3 = (const float*)d_in[11];
    const float* ad3 = (const float*)d_in[12];
    const float* b3  = (const float*)d_in[13];

    const int d1 = in_sizes[3];                    // 256
    const int C  = in_sizes[2] / d1;               // 128
    const int N  = in_sizes[0] / C;                // 50000
    const int E  = in_sizes[1] / 2;                // 800000
    const int d2 = in_sizes[7];                    // 64
    const int ET = E + N;                          // 850000

    char* p = (char*)d_ws;
    auto alloc = [&](size_t bytes) -> void* {
        void* q = (void*)p;
        p += (bytes + 255) & ~(size_t)255;
        return q;
    };
    int*    offsets = (int*)alloc(sizeof(int) * (size_t)(N + 1));
    int*    cursor  = (int*)alloc(sizeof(int) * (size_t)N);
    int*    bsums   = (int*)alloc(sizeof(int) * 256);
    int*    csr     = (int*)alloc(sizeof(int) * (size_t)ET);
    float*  asb1    = (float*)alloc(sizeof(float) * (size_t)N);
    float*  adb1    = (float*)alloc(sizeof(float) * (size_t)N);
    float*  alpha2  = (float*)alloc(sizeof(float) * (size_t)2 * N);  // as2b, ad2b
    float*  as2b = alpha2, *ad2b = alpha2 + N;
    float*  wvec    = (float*)alloc(sizeof(float) * 256);
    __half* xf      = (__half*)alloc(sizeof(__half) * (size_t)N * C);
    __half* zbuf    = (__half*)alloc(sizeof(__half) * (size_t)N * C);
    __half* w1t     = (__half*)alloc(sizeof(__half) * (size_t)C * d1);
    __half* w2t     = (__half*)alloc(sizeof(__half) * (size_t)d1 * d2);
    __half* o1      = (__half*)alloc(sizeof(__half) * (size_t)N * d1);
    __half* ch2     = (__half*)alloc(sizeof(__half) * (size_t)N * d2);
    float*  h3      = (float*)alloc(sizeof(float) * (size_t)N);
    float*  as3b    = (float*)alloc(sizeof(float) * (size_t)N);
    float*  ad3b    = (float*)alloc(sizeof(float) * (size_t)N);

    const int eb  = (ET + 255) / 256;
    const int nch = (N + 255) / 256;
    const int wb  = (N + 3) / 4;

    // ---- layer-1 logit weight vectors (once) ----
    wvec_k<<<1, 256, 0, stream>>>(W1, as1, ad1, wvec, C, d1);

    // ---- prep0: zero + converts + layer-1 logits ----
    prep0_k<<<1024, 256, 0, stream>>>(cursor, alpha2, N,
                                      x, xf, W1, w1t, W2, w2t,
                                      wvec, asb1, adb1, C, d1, d2);

    // ---- CSR build ----
    hist_k<<<eb, 256, 0, stream>>>(ei, E, N, cursor);
    scan1_k<<<nch, 256, 0, stream>>>(cursor, offsets, bsums, N);
    scan2_k<<<1, 256, 0, stream>>>(bsums, nch);
    scan3_k<<<nch, 256, 0, stream>>>(offsets, cursor, bsums, N, ET);
    fill_k<<<eb, 256, 0, stream>>>(ei, E, N, cursor, csr);

    // ---- layer 1: aggregate x (128-dim), then GEMM with fused bias+ELU+logits ----
    agg1x_k<<<wb, 256, 0, stream>>>(offsets, csr, asb1, adb1, xf, zbuf, N);
    {
        dim3 g((N + 127) / 128, d1 / 64);
        gemm1_k<<<g, 256, 0, stream>>>((const ushort*)zbuf, (const ushort*)w1t,
                                       o1, N, C, d1, b1, W2, d2, as2, ad2, as2b, ad2b);
    }
    // ---- layer 2: GEMM (256->64), aggregate 64-dim, fused layer-3 prep ----
    {
        dim3 g((N + 127) / 128, d2 / 64);
        gemm2_k<<<g, 256, 0, stream>>>((const ushort*)o1, (const ushort*)w2t,
                                       ch2, N, d1, d2);
    }
    agg2_k<<<wb, 256, 0, stream>>>(offsets, csr, as2b, ad2b, ch2, b2,
                                   W3, as3, ad3, h3, as3b, ad3b, N);
    // ---- layer 3: aggregation ----
    agg3_k<<<wb, 256, 0, stream>>>(offsets, csr, as3b, ad3b, h3, b3, (float*)d_out, N);
}